// Round 6
// baseline (4078.279 us; speedup 1.0000x reference)
//
#include <hip/hip_runtime.h>
#include <hip/hip_bf16.h>

#define H   2048
#define V   32000
#define SS  64
#define EE  512
#define BB  8
#define PP  16
#define LL  8
#define TT  32
#define TP1 33
#define BSZ 512   // B*S
#define NEGV -1e30f

typedef unsigned short u16;
typedef unsigned int   u32;
typedef short bf16x8 __attribute__((ext_vector_type(8)));
typedef float f32x4  __attribute__((ext_vector_type(4)));

__device__ __forceinline__ float bf2f(u16 x){ return __uint_as_float(((u32)x) << 16); }
__device__ __forceinline__ u16 f2bf(float f){
  u32 u = __float_as_uint(f);
  return (u16)((u + 0x7fffu + ((u >> 16) & 1u)) >> 16);
}
// monotonic float<->uint encoding for atomicMax on possibly-negative floats; init 0 is below enc(-inf)
__device__ __forceinline__ u32 encf(float f){ u32 u = __float_as_uint(f); return (u & 0x80000000u) ? ~u : (u | 0x80000000u); }
__device__ __forceinline__ float decf(u32 e){ u32 u = (e & 0x80000000u) ? (e & 0x7fffffffu) : ~e; return __uint_as_float(u); }

// XOR-swizzled index for transposed [n][k] LDS tiles with row stride 40 u16.
__device__ __forceinline__ int bswz(int n, int kr){
  return ((n*40 + (kr & ~7)) ^ ((n>>1) & 56)) + (kr & 7);
}
__device__ __forceinline__ int bswz_rd(int n, int k8){   // read base of 8 contiguous k at k8 (mult of 8)
  return (n*40 + k8) ^ ((n>>1) & 56);
}

// -------- software grid barrier (graph-capture-safe; all blocks guaranteed resident) --------
// monotonic counter in zeroed ws; target = nblk * (barrier ordinal). Release: syncthreads +
// threadfence (L2 writeback) before increment. Acquire: device-scope atomic spin + all-thread
// threadfence. Spin is BOUNDED so a liveness bug shows as absmax-fail, not a container kill.
__device__ __forceinline__ void gridbar(u32* bar, u32 target){
  __syncthreads();
  if (threadIdx.x == 0){
    __threadfence();
    atomicAdd(bar, 1u);
    for (int spin = 0; spin < (1<<24); ++spin){
      if (atomicAdd(bar, 0u) >= target) break;
      __builtin_amdgcn_s_sleep(1);
    }
  }
  __syncthreads();
  __threadfence();
}

// ---------------- beta: rowlse + expB (bf16), register-resident 3-pass ----------------
__global__ __launch_bounds__(512) void k_beta(const float* __restrict__ braw, float* __restrict__ rowlse, u16* __restrict__ expB){
  int h = blockIdx.x, t = threadIdx.x;
  __shared__ float red[8];
  __shared__ float red2[8];
  const float* row = braw + (size_t)h * V;
  uint2 stash[16];
  float m = -INFINITY;
  #pragma unroll
  for (int it = 0; it < 16; ++it){
    int idx = (it*512 + t)*4;
    if (idx < V){
      float4 x = *(const float4*)(row + idx);
      u16 b0=f2bf(x.x), b1=f2bf(x.y), b2=f2bf(x.z), b3=f2bf(x.w);
      stash[it] = make_uint2(((u32)b1<<16)|b0, ((u32)b3<<16)|b2);
      m = fmaxf(m, fmaxf(fmaxf(x.x,x.y),fmaxf(x.z,x.w)));
    }
  }
  for (int off=32; off; off>>=1) m = fmaxf(m, __shfl_xor(m, off, 64));
  if ((t&63)==0) red[t>>6] = m;
  __syncthreads();
  m = red[0];
  #pragma unroll
  for (int wv=1; wv<8; ++wv) m = fmaxf(m, red[wv]);
  float s0=0.f, s1=0.f;
  #pragma unroll
  for (int it = 0; it < 16; ++it){
    int idx = (it*512 + t)*4;
    if (idx < V){
      uint2 pk = stash[it];
      float e0 = expf(bf2f((u16)(pk.x      )) - m);
      float e1 = expf(bf2f((u16)(pk.x >> 16)) - m);
      float e2 = expf(bf2f((u16)(pk.y      )) - m);
      float e3 = expf(bf2f((u16)(pk.y >> 16)) - m);
      stash[it] = make_uint2(((u32)f2bf(e1)<<16)|f2bf(e0), ((u32)f2bf(e3)<<16)|f2bf(e2));
      s0 += e0 + e2; s1 += e1 + e3;
    }
  }
  float s = s0 + s1;
  for (int off=32; off; off>>=1) s += __shfl_xor(s, off, 64);
  if ((t&63)==0) red2[t>>6] = s;
  __syncthreads();
  s = (red2[0]+red2[1])+(red2[2]+red2[3])+(red2[4]+red2[5])+(red2[6]+red2[7]);
  if (t == 0) rowlse[h] = m + logf(s);
  float inv = 1.f / s;
  u16* orow = expB + (size_t)h*V;
  #pragma unroll
  for (int it = 0; it < 16; ++it){
    int idx = (it*512 + t)*4;
    if (idx < V){
      uint2 pk = stash[it];
      u16 a0 = f2bf(bf2f((u16)(pk.x      )) * inv);
      u16 a1 = f2bf(bf2f((u16)(pk.x >> 16)) * inv);
      u16 a2 = f2bf(bf2f((u16)(pk.y      )) * inv);
      u16 a3 = f2bf(bf2f((u16)(pk.y >> 16)) * inv);
      *(uint2*)(orow + idx) = make_uint2(((u32)a1<<16)|a0, ((u32)a3<<16)|a2);
    }
  }
}

// ---------------- alpha row softmax -> f32 + bf16 ----------------
__global__ __launch_bounds__(256) void k_alpha(const float* __restrict__ a, float* __restrict__ af, u16* __restrict__ abf){
  int r = blockIdx.x, t = threadIdx.x;
  __shared__ float ld[H];
  __shared__ float red[8];
  const float* row = a + (size_t)r * H;
  for (int i=0;i<8;++i){ int j=i*256+t; ld[j]=row[j]; }
  __syncthreads();
  float m=-INFINITY; for(int i=0;i<8;++i) m=fmaxf(m, ld[i*256+t]);
  for(int off=32;off;off>>=1) m=fmaxf(m,__shfl_xor(m,off,64));
  if((t&63)==0) red[t>>6]=m;
  __syncthreads();
  m=fmaxf(fmaxf(red[0],red[1]),fmaxf(red[2],red[3]));
  float s=0.f; for(int i=0;i<8;++i) s+=expf(ld[i*256+t]-m);
  for(int off=32;off;off>>=1) s+=__shfl_xor(s,off,64);
  if((t&63)==0) red[4+(t>>6)]=s;
  __syncthreads();
  s=red[4]+red[5]+red[6]+red[7];
  float inv=1.f/s;
  for(int i=0;i<8;++i){ int j=i*256+t; float e=expf(ld[j]-m)*inv; af[(size_t)r*H+j]=e; abf[(size_t)r*H+j]=f2bf(e); }
}

// ---------------- gamma log_softmax ----------------
__global__ __launch_bounds__(256) void k_gamma(const float* __restrict__ graw, float* __restrict__ G){
  int t = threadIdx.x;
  __shared__ float ld[H]; __shared__ float red[8];
  for (int i=0;i<8;++i){ int j=i*256+t; ld[j]=graw[j]; }
  __syncthreads();
  float m=-INFINITY; for(int i=0;i<8;++i) m=fmaxf(m, ld[i*256+t]);
  for(int off=32;off;off>>=1) m=fmaxf(m,__shfl_xor(m,off,64));
  if((t&63)==0) red[t>>6]=m;
  __syncthreads();
  m=fmaxf(fmaxf(red[0],red[1]),fmaxf(red[2],red[3]));
  float s=0.f; for(int i=0;i<8;++i) s+=expf(ld[i*256+t]-m);
  for(int off=32;off;off>>=1) s+=__shfl_xor(s,off,64);
  if((t&63)==0) red[4+(t>>6)]=s;
  __syncthreads();
  s=red[4]+red[5]+red[6]+red[7];
  float lse=m+logf(s);
  for(int i=0;i<8;++i){ int j=i*256+t; G[j]=ld[j]-lse; }
}

// ---------------- per (prefix step,b): max_h beta[h,tok] ----------------
__global__ __launch_bounds__(256) void k_prefd(const float* __restrict__ braw, const float* __restrict__ rowlse, const int* __restrict__ pref, float* __restrict__ D){
  int blk = blockIdx.x; int ts = blk >> 3, b = blk & 7; int t = threadIdx.x;
  int tok = pref[b*PP + ts];
  float m = -INFINITY;
  for (int i=0;i<8;++i){ int hh=i*256+t; m = fmaxf(m, braw[(size_t)hh*V + tok] - rowlse[hh]); }
  __shared__ float red[4];
  for(int off=32;off;off>>=1) m=fmaxf(m,__shfl_xor(m,off,64));
  if((t&63)==0) red[t>>6]=m;
  __syncthreads();
  if (t==0) D[ts*BB + b] = fmaxf(fmaxf(red[0],red[1]),fmaxf(red[2],red[3]));
}

// ---------------- masks -> bf16 ----------------
__global__ __launch_bounds__(256) void k_mask(const float* __restrict__ EV, const float* __restrict__ VE, u16* __restrict__ EVbf, u16* __restrict__ VEbf){
  int idx = blockIdx.x*256 + threadIdx.x;  // 32768
  EVbf[idx] = f2bf(EV[idx]);
  VEbf[idx] = f2bf(VE[idx]);
}

// ---------------- T_mask f32 -> bf16 (exact: 0/1) ----------------
__global__ __launch_bounds__(256) void k_cvtT(const float* __restrict__ T, u16* __restrict__ Tbf){
  int i = (blockIdx.x*256 + threadIdx.x)*4;   // grid 16000
  float4 x = *(const float4*)(T + i);
  *(uint2*)(Tbf + i) = make_uint2(((u32)f2bf(x.y)<<16)|f2bf(x.x), ((u32)f2bf(x.w)<<16)|f2bf(x.z));
}

// ---------------- A3[bs][e] = VE[states[b],e]*EV[e,s] ----------------
__global__ __launch_bounds__(256) void k_a3(const float* __restrict__ VE, const float* __restrict__ EV, const int* __restrict__ states, u16* __restrict__ A3){
  int idx = blockIdx.x*256 + threadIdx.x;  // 262144
  int bs = idx >> 9, e = idx & 511;
  int b = bs >> 6, s = bs & 63;
  A3[idx] = f2bf(VE[states[b]*EE + e] * EV[e*SS + s]);
}

// ---------------- A-cache scan, ALL steps fused (software grid barrier, grid 256) ----------------
__global__ __launch_bounds__(256) void k_ascan_all(const float* __restrict__ braw, const float* __restrict__ rowlse,
    const float* __restrict__ alpha_f, const float* __restrict__ G, const float* __restrict__ D,
    const int* __restrict__ pref, float* __restrict__ PA, u32* __restrict__ MAXPA, float* __restrict__ MUA,
    u32* __restrict__ bar){
  int bid = blockIdx.x; int kc = bid & 31, jt = bid >> 5; int t = threadIdx.x;   // grid 256
  __shared__ float ey[BB][64];
  __shared__ float wred[4][BB];
  u32 nb = 0;
  for (int ts = 1; ts <= PP; ++ts){
    const float* PAprev = PA + (size_t)(ts-1)*BB*H;
    float* PAcur = PA + (size_t)ts*BB*H;
    for (int i = 0; i < 2; ++i){
      int idx = i*256 + t; int b = idx >> 6, hl = idx & 63; int hh = kc*64 + hl;
      int tok = pref[b*PP + (ts-1)];
      float bcol = braw[(size_t)hh*V + tok] - rowlse[hh];
      float Db = D[(ts-1)*BB + b];
      float v;
      if (ts == 1){
        v = expf(G[hh] + bcol - Db);
      } else {
        float p = PAprev[b*H + hh];
        float mp = fmaxf(__uint_as_float(MAXPA[(ts-1)*BB + b]), 1e-30f);
        v = p > 0.f ? p * (1.f/mp) * expf(bcol - Db) : 0.f;
      }
      ey[b][hl] = v;
    }
    __syncthreads();
    int j = jt*256 + t;
    float acc[BB];
    #pragma unroll
    for (int b=0;b<BB;++b) acc[b]=0.f;
    for (int hl = 0; hl < 64; ++hl){
      float a = alpha_f[(size_t)(kc*64 + hl)*H + j];
      #pragma unroll
      for (int b=0;b<BB;++b) acc[b] += ey[b][hl] * a;
    }
    #pragma unroll
    for (int b=0;b<BB;++b){
      atomicAdd(&PAcur[b*H + j], acc[b]);
      float mv = acc[b];
      for (int off=32;off;off>>=1) mv = fmaxf(mv, __shfl_xor(mv, off, 64));
      if ((t&63)==0) wred[t>>6][b] = mv;
    }
    __syncthreads();
    if (t < BB){
      float mv = fmaxf(fmaxf(wred[0][t],wred[1][t]),fmaxf(wred[2][t],wred[3][t]));
      atomicMax(&MAXPA[ts*BB + t], __float_as_uint(fmaxf(mv, 0.f)));
    }
    if (bid == 0 && t < BB){
      float mu = MUA[(ts-1)*BB + t];
      if (ts > 1) mu += logf(fmaxf(__uint_as_float(MAXPA[(ts-1)*BB + t]), 1e-30f));
      MUA[ts*BB + t] = mu + D[(ts-1)*BB + t];
    }
    ++nb; gridbar(bar, 256u*nb);
  }
}

// ---------------- suffix backward, ALL steps fused (software grid barrier, grid 256, 8 rows/block) ----------------
__global__ __launch_bounds__(256) void k_sufall(const float* __restrict__ braw, const float* __restrict__ rowlse,
    const float* __restrict__ alpha_f, const int* __restrict__ suffix, float* __restrict__ YS,
    u32* __restrict__ bar){
  int t = threadIdx.x, blk = blockIdx.x;   // grid 256
  __shared__ float ye[H]; __shared__ float red[4];
  int tok_in = suffix[LL-1];
  u32 nb = 0;
  for (int step = 0; step < LL-1; ++step){
    const float* src = YS + (step & 1)*H;
    float* dst = YS + (1 - (step & 1))*H;
    for (int i=0;i<8;++i){
      int jj = i*256 + t;
      ye[jj] = (step == 0) ? (braw[(size_t)jj*V + tok_in] - rowlse[jj]) : src[jj];
    }
    __syncthreads();
    float m=-INFINITY;
    for(int i=0;i<8;++i) m=fmaxf(m, ye[i*256+t]);
    for(int off=32;off;off>>=1) m=fmaxf(m,__shfl_xor(m,off,64));
    if((t&63)==0) red[t>>6]=m;
    __syncthreads();
    m=fmaxf(fmaxf(red[0],red[1]),fmaxf(red[2],red[3]));
    for (int i=0;i<8;++i){ int jj=i*256+t; ye[jj] = expf(ye[jj]-m); }
    __syncthreads();
    int w = t >> 6, lane = t & 63;
    int tok = suffix[LL-2-step];
    #pragma unroll
    for (int sub = 0; sub < 2; ++sub){
      int r = blk*8 + w*2 + sub;
      float acc = 0.f;
      for (int k2=0;k2<32;++k2){ int jj=k2*64+lane; acc += alpha_f[(size_t)r*H + jj]*ye[jj]; }
      for(int off=32;off;off>>=1) acc += __shfl_xor(acc,off,64);
      if (lane==0) dst[r] = logf(acc) + m + (braw[(size_t)r*V + tok] - rowlse[r]);
    }
    ++nb; gridbar(bar, 256u*nb);
  }
}

// ---------------- C-scan t=0 prep: Y2T = accept-masked y_suf, MU2[0] ----------------
__global__ __launch_bounds__(256) void k_c0(const float* __restrict__ YS, const float* __restrict__ accept, float* __restrict__ Y2T, u32* __restrict__ MU2){
  int blk = blockIdx.x, t = threadIdx.x;   // grid 64
  const float* ysuf = YS + H;
  int h0 = blk*32;
  for (int i=0;i<8;++i){
    int idx = i*256 + t; int r = idx >> 6, s = idx & 63;
    Y2T[(size_t)(h0+r)*SS + s] = accept[s] > 0.f ? ysuf[h0 + r] : NEGV;
  }
  if (blk == 0){
    __shared__ float red[4];
    float m=-INFINITY;
    for(int i=0;i<8;++i) m = fmaxf(m, ysuf[i*256+t]);
    for(int off=32;off;off>>=1) m=fmaxf(m,__shfl_xor(m,off,64));
    if((t&63)==0) red[t>>6]=m;
    __syncthreads();
    if (t < SS){
      float mm = fmaxf(fmaxf(red[0],red[1]),fmaxf(red[2],red[3]));
      MU2[t] = encf(accept[t] > 0.f ? mm : NEGV);
    }
  }
}

// ---------------- pgemm body: PT[j][s] += sum_h exp(Y2T-mu)*alpha[j][h] (split-K 16, 256 blocks) ----------------
__device__ __forceinline__ void pgemm_body(int bid, int t, const u16* __restrict__ abf,
    const float* __restrict__ Y2T, const u32* __restrict__ MU2t, float* __restrict__ PTt,
    u16* Alds, u16* Blds, float* muld){
  int kc = bid & 15, mt = bid >> 4;
  if (t < SS) muld[t] = decf(MU2t[t]);
  __syncthreads();
  int m0 = mt*128;
  int w = t >> 6, lane = t & 63, l15 = lane & 15, q = lane >> 4;
  f32x4 acc[2][4];
  for(int a=0;a<2;++a)for(int b=0;b<4;++b)for(int c=0;c<4;++c) acc[a][b][c]=0.f;
  for (int it=0; it<4; ++it){
    int kb = kc*128 + it*32;
    { int row = t >> 1, cg_ = (t & 1)*16;
      const u16* src = abf + (size_t)(m0+row)*H + kb + cg_;
      *(uint4*)&Alds[row*40+cg_]   = *(const uint4*)src;
      *(uint4*)&Alds[row*40+cg_+8] = *(const uint4*)(src+8);
    }
    for (int i=0;i<8;++i){
      int idx = i*256 + t; int kr = idx >> 6, s = idx & 63;
      float y = Y2T[(size_t)(kb+kr)*SS + s];
      Blds[bswz(s, kr)] = f2bf(expf(y - muld[s]));
    }
    __syncthreads();
    bf16x8 bv[4];
    #pragma unroll
    for (int nf=0; nf<4; ++nf){ int nn = nf*16 + l15; bv[nf] = *(bf16x8*)&Blds[bswz_rd(nn, q*8)]; }
    #pragma unroll
    for (int mf=0; mf<2; ++mf){
      bf16x8 a = *(bf16x8*)&Alds[(w*32 + mf*16 + l15)*40 + q*8];
      #pragma unroll
      for (int nf=0; nf<4; ++nf)
        acc[mf][nf] = __builtin_amdgcn_mfma_f32_16x16x32_bf16(a, bv[nf], acc[mf][nf], 0, 0, 0);
    }
    __syncthreads();
  }
  #pragma unroll
  for (int mf=0;mf<2;++mf)
  #pragma unroll
  for (int nf=0;nf<4;++nf)
  #pragma unroll
  for (int reg=0;reg<4;++reg){
    int j = m0 + w*32 + mf*16 + q*4 + reg;
    int s = nf*16 + l15;
    atomicAdd(&PTt[(size_t)j*SS + s], acc[mf][nf][reg]);
  }
}

// ---------------- cstep body: EV-lse -> +Tw -> VE-lse, 128 blocks x 16 h-rows ----------------
__device__ __forceinline__ void cstep_body(int blk, int t, const float* __restrict__ PTprev,
    const u32* __restrict__ MU2prev, const float* __restrict__ TwT, const u16* __restrict__ EVbf,
    const u16* __restrict__ VEbf, float* __restrict__ Y2T, u32* __restrict__ MU2t,
    float* ytile, float* muprev, float* mx, u32* mzenc, float* mzf, u16* EYl, u16* EZl){
  int h0 = blk*16;
  if (t < SS) muprev[t] = decf(MU2prev[t]);
  if (t >= 64 && t < 80) mzenc[t-64] = 0u;
  __syncthreads();
  for (int i=0;i<4;++i){
    int idx = i*256 + t; int r = idx >> 6, s = idx & 63;
    float p = PTprev[(size_t)(h0+r)*SS + s];
    ytile[r*64+s] = (p > 0.f) ? (logf(p) + muprev[s]) : NEGV;
  }
  __syncthreads();
  { int r = t >> 4, i4 = t & 15;
    float m = ytile[r*64 + i4*4];
    m = fmaxf(m, ytile[r*64 + i4*4 + 1]);
    m = fmaxf(m, ytile[r*64 + i4*4 + 2]);
    m = fmaxf(m, ytile[r*64 + i4*4 + 3]);
    for (int d=1; d<16; d<<=1) m = fmaxf(m, __shfl_xor(m, d, 64));
    if (i4 == 0) mx[r] = m;
  }
  __syncthreads();
  for (int i=0;i<4;++i){
    int idx = i*256 + t; int r = idx >> 6, s = idx & 63;
    EYl[r*72 + s] = f2bf(expf(ytile[r*64+s] - mx[r]));
  }
  __syncthreads();
  int w = t >> 6, lane = t & 63, l15 = lane & 15, q = lane >> 4;
  f32x4 acc1[8];
  for (int nf=0;nf<8;++nf) for(int c=0;c<4;++c) acc1[nf][c]=0.f;
  #pragma unroll
  for (int kf=0; kf<2; ++kf){
    bf16x8 a = *(bf16x8*)&EYl[l15*72 + kf*32 + q*8];
    #pragma unroll
    for (int nf=0; nf<8; ++nf){
      int e = w*128 + nf*16 + l15;
      bf16x8 b = *(const bf16x8*)&EVbf[(size_t)e*SS + kf*32 + q*8];
      acc1[nf] = __builtin_amdgcn_mfma_f32_16x16x32_bf16(a, b, acc1[nf], 0, 0, 0);
    }
  }
  #pragma unroll
  for (int nf=0; nf<8; ++nf){
    int e = w*128 + nf*16 + l15;
    #pragma unroll
    for (int reg=0; reg<4; ++reg){
      int r = q*4 + reg;
      float S1 = acc1[nf][reg];
      acc1[nf][reg] = (S1 > 0.f ? (logf(S1) + mx[r]) : NEGV) + TwT[(size_t)(h0+r)*EE + e];
    }
  }
  #pragma unroll
  for (int reg=0; reg<4; ++reg){
    float zm = acc1[0][reg];
    #pragma unroll
    for (int nf=1; nf<8; ++nf) zm = fmaxf(zm, acc1[nf][reg]);
    for (int d=1; d<16; d<<=1) zm = fmaxf(zm, __shfl_xor(zm, d, 64));
    if (l15 == 0) atomicMax(&mzenc[q*4 + reg], encf(zm));
  }
  __syncthreads();
  if (t < 16) mzf[t] = decf(mzenc[t]);
  __syncthreads();
  #pragma unroll
  for (int nf=0; nf<8; ++nf){
    int e = w*128 + nf*16 + l15;
    #pragma unroll
    for (int reg=0; reg<4; ++reg){
      int r = q*4 + reg;
      EZl[r*520 + e] = f2bf(expf(acc1[nf][reg] - mzf[r]));
    }
  }
  __syncthreads();
  f32x4 acc2;
  for(int c=0;c<4;++c) acc2[c]=0.f;
  #pragma unroll
  for (int kc2=0; kc2<16; ++kc2){
    bf16x8 a = *(bf16x8*)&EZl[l15*520 + kc2*32 + q*8];
    bf16x8 b = *(const bf16x8*)&VEbf[(size_t)(w*16 + l15)*EE + kc2*32 + q*8];
    acc2 = __builtin_amdgcn_mfma_f32_16x16x32_bf16(a, b, acc2, 0, 0, 0);
  }
  int s = w*16 + l15;
  float cm = -INFINITY;
  #pragma unroll
  for (int reg=0; reg<4; ++reg){
    int r = q*4 + reg;
    float S2 = acc2[reg];
    float y2 = S2 > 0.f ? (logf(S2) + mzf[r]) : NEGV;
    Y2T[(size_t)(h0+r)*SS + s] = y2;
    cm = fmaxf(cm, y2);
  }
  cm = fmaxf(cm, __shfl_xor(cm, 16, 64));
  cm = fmaxf(cm, __shfl_xor(cm, 32, 64));
  if (q == 0) atomicMax(&MU2t[s], encf(cm));
}

// ---------------- whole C-scan fused (software grid barrier, grid 256) ----------------
__global__ __launch_bounds__(256) void k_scan(const u16* __restrict__ abf, float* __restrict__ PT,
    u32* __restrict__ MU2, float* __restrict__ Y2T, const float* __restrict__ TwT,
    const u16* __restrict__ EVbf, const u16* __restrict__ VEbf, u32* __restrict__ bar){
  int blk = blockIdx.x, t = threadIdx.x;
  __shared__ float ytile[16*64];
  __shared__ float muprev[SS];
  __shared__ float mx[16];
  __shared__ u32 mzenc[16];
  __shared__ float mzf[16];
  __shared__ u16 EYl[16*72];
  __shared__ u16 EZl[16*520];
  __shared__ u16 Alds[128*40];
  __shared__ u16 Bl2[64*40];
  __shared__ float muld[SS];
  u32 nb = 0;
  for (int ts = 0; ts <= TT; ++ts){
    if (ts > 0){
      if (blk < 128)
        cstep_body(blk, t, PT + (size_t)(ts-1)*H*SS, MU2 + (size_t)(ts-1)*SS, TwT, EVbf, VEbf,
                   Y2T, MU2 + (size_t)ts*SS, ytile, muprev, mx, mzenc, mzf, EYl, EZl);
      ++nb; gridbar(bar, 256u*nb);
    }
    pgemm_body(blk, t, abf, Y2T, MU2 + (size_t)ts*SS, PT + (size_t)ts*H*SS, Alds, Bl2, muld);
    ++nb; gridbar(bar, 256u*nb);
  }
}

// ---------------- TwT GEMM: TwT[h][e] += sum_v expB[h,v]*Tbf[e,v]; both NT bf16 ----------------
__global__ __launch_bounds__(256) void k_twgemm(const u16* __restrict__ Abf, const u16* __restrict__ Bbf, float* __restrict__ Cacc){
  int bid = blockIdx.x; int t = threadIdx.x;   // grid 640 = 16 mt * 4 nt * 10 kc
  int kc = bid % 10; int rest = bid / 10;
  int nt = rest & 3; int mt = rest >> 2;
  int m0 = mt*128, n0 = nt*128;
  __shared__ u16 Alds[128*40];
  __shared__ u16 Blds[128*40];
  int w = t>>6, lane = t&63, l15 = lane&15, q = lane>>4;
  int wm = w >> 1, wn = w & 1;
  f32x4 acc[4][4];
  for(int a=0;a<4;++a)for(int b=0;b<4;++b)for(int c=0;c<4;++c)acc[a][b][c]=0.f;
  for (int it=0; it<100; ++it){
    int kb = (kc*100 + it)*32;
    { int row = t>>1, cg = (t&1)*16;
      const u16* srcA = Abf + (size_t)(m0+row)*V + kb + cg;
      *(uint4*)&Alds[row*40+cg]   = *(const uint4*)srcA;
      *(uint4*)&Alds[row*40+cg+8] = *(const uint4*)(srcA+8);
      const u16* srcB = Bbf + (size_t)(n0+row)*V + kb + cg;
      *(uint4*)&Blds[row*40+cg]   = *(const uint4*)srcB;
      *(uint4*)&Blds[row*40+cg+8] = *(const uint4*)(srcB+8);
    }
    __syncthreads();
    bf16x8 av[4], bv[4];
    #pragma unroll
    for (int mf=0;mf<4;++mf) av[mf] = *(bf16x8*)&Alds[(wm*64+mf*16+l15)*40 + q*8];
    #pragma unroll
    for (int nf=0;nf<4;++nf) bv[nf] = *(bf16x8*)&Blds[(wn*64+nf*16+l15)*40 + q*8];
    #pragma unroll
    for (int mf=0;mf<4;++mf)
      #pragma unroll
      for (int nf=0;nf<4;++nf)
        acc[mf][nf] = __builtin_amdgcn_mfma_f32_16x16x32_bf16(av[mf], bv[nf], acc[mf][nf], 0, 0, 0);
    __syncthreads();
  }
  #pragma unroll
  for (int mf=0;mf<4;++mf)
  #pragma unroll
  for (int nf=0;nf<4;++nf)
  #pragma unroll
  for (int reg=0;reg<4;++reg){
    int m = m0 + wm*64 + mf*16 + q*4 + reg;
    int n = n0 + wn*64 + nf*16 + l15;
    atomicAdd(&Cacc[(size_t)m*EE + n], acc[mf][nf][reg]);
  }
}

// ---------------- TwT = n2n(log(TwTacc)) in place ----------------
__global__ __launch_bounds__(256) void k_twlog(float* __restrict__ TwT){
  int idx = blockIdx.x*256 + threadIdx.x;
  float v = TwT[idx];
  TwT[idx] = v > 0.f ? logf(v) : NEGV;
}

// ---------------- range aggregation + A add -> Cfull, M1 ----------------
__global__ __launch_bounds__(256) void k_range(const float* __restrict__ PT, const u32* __restrict__ MU2,
    const float* __restrict__ rmask, const float* __restrict__ PA, const float* __restrict__ MUA,
    float* __restrict__ Cfull, u32* __restrict__ M1e){
  int blk = blockIdx.x, t = threadIdx.x; int h0 = blk*16;   // grid 128
  __shared__ float muf[TP1*SS];
  __shared__ float rm[BB*TP1];
  __shared__ float muA[BB];
  for (int i = t; i < TP1*SS; i += 256) muf[i] = decf(MU2[i]);
  for (int i = t; i < BB*TP1; i += 256) rm[i] = rmask[i];
  if (t < BB) muA[t] = MUA[16*BB + t];
  __syncthreads();
  const float* PA16 = PA + (size_t)16*BB*H;
  int s = t & 63; int hb = t >> 6;
  float tmax[BB];
  #pragma unroll
  for (int b=0;b<BB;++b) tmax[b] = -INFINITY;
  for (int i=0;i<4;++i){
    int h = h0 + hb*4 + i;
    float c[TP1];
    float M = -INFINITY;
    #pragma unroll
    for (int tt=0; tt<TP1; ++tt){
      float p = PT[(size_t)tt*(H*SS) + (size_t)h*SS + s];
      float cv = p > 0.f ? (logf(p) + muf[tt*SS + s]) : NEGV;
      c[tt] = cv; M = fmaxf(M, cv);
    }
    #pragma unroll
    for (int tt=0; tt<TP1; ++tt) c[tt] = expf(c[tt] - M);
    #pragma unroll
    for (int b=0;b<BB;++b){
      float a = 0.f;
      #pragma unroll
      for (int tt=0; tt<TP1; ++tt) a += rm[b*TP1 + tt]*c[tt];
      float cr = a > 0.f ? (logf(a) + M) : NEGV;
      float pa = PA16[b*H + h];
      float Ab = pa > 0.f ? (logf(pa) + muA[b]) : NEGV;
      float cf = Ab + cr;
      Cfull[((size_t)(b*SS + s))*H + h] = cf;
      tmax[b] = fmaxf(tmax[b], cf);
    }
  }
  #pragma unroll
  for (int b=0;b<BB;++b) atomicMax(&M1e[b*SS + s], encf(tmax[b]));
}

// ---------------- mb[b] = max_s M1[b,s]; W[b,s] = exp(M1-mb) ----------------
__global__ void k_mb(const u32* __restrict__ M1e, float* __restrict__ W, float* __restrict__ MB){
  int t = threadIdx.x;   // 512 threads; wave id == b
  float m1 = decf(M1e[t]);
  float m = m1;
  for (int off=32; off; off>>=1) m = fmaxf(m, __shfl_xor(m, off, 64));
  if ((t&63)==0) MB[t>>6] = m;
  W[t] = expf(m1 - m);
}

// ---------------- expCf bf16 ----------------
__global__ __launch_bounds__(256) void k_expcf(const float* __restrict__ Cfull, const u32* __restrict__ M1e, u16* __restrict__ expCf){
  int idx = blockIdx.x*256 + threadIdx.x;
  int bs = idx >> 11;
  expCf[idx] = f2bf(expf(Cfull[idx] - decf(M1e[bs])));
}

// ---------------- expA / maxA for logits_ ----------------
__global__ __launch_bounds__(256) void k_expa(const float* __restrict__ PA, const float* __restrict__ MUA, u16* __restrict__ expA, float* __restrict__ maxA){
  int b = blockIdx.x, t = threadIdx.x;
  const float* PA16 = PA + (size_t)16*BB*H + (size_t)b*H;
  __shared__ float al[H]; __shared__ float red[4];
  float mua = MUA[16*BB + b];
  for (int i=0;i<8;++i){ int h=i*256+t; float p=PA16[h]; al[h] = p>0.f ? (logf(p)+mua) : NEGV; }
  __syncthreads();
  float m=-INFINITY; for(int i=0;i<8;++i) m=fmaxf(m, al[i*256+t]);
  for(int off=32;off;off>>=1) m=fmaxf(m,__shfl_xor(m,off,64));
  if((t&63)==0) red[t>>6]=m;
  __syncthreads();
  m=fmaxf(fmaxf(red[0],red[1]),fmaxf(red[2],red[3]));
  if (t==0) maxA[b]=m;
  for (int i=0;i<8;++i){ int h=i*256+t; expA[b*H+h]=f2bf(expf(al[h]-m)); }
}

// ---------------- fused logits: S2 (K=512) stash, S1 (K=2048), combine + lse_s in-register ----------------
__global__ __launch_bounds__(256) void k_flog(const u16* __restrict__ expCf, const u16* __restrict__ expB,
    const u16* __restrict__ A3, const u16* __restrict__ Tbf,
    const float* __restrict__ W, const float* __restrict__ MB, float* __restrict__ out){
  int bid = blockIdx.x; int t = threadIdx.x;   // grid 1000 = 4 mt * 250 nt
  int nt = bid % 250, mt = bid / 250;
  int m0 = mt*128, n0 = nt*128;
  __shared__ u16 Alds[128*40];
  __shared__ u16 Blds[128*40];
  __shared__ float Wl[BSZ];
  for (int i=t; i<BSZ; i+=256) Wl[i] = W[i];
  int w = t>>6, lane = t&63, l15 = lane&15, q = lane>>4;
  int wm = w >> 1, wn = w & 1;
  f32x4 acc[4][4];
  for(int a=0;a<4;++a)for(int b=0;b<4;++b)for(int c=0;c<4;++c)acc[a][b][c]=0.f;
  // ---- phase 1: S2 = A3 @ Tbf (K=EE) ----
  for (int it=0; it<16; ++it){
    int kb = it*32;
    { int row = t>>1, cg = (t&1)*16;
      const u16* src = A3 + (size_t)(m0+row)*EE + kb + cg;
      *(uint4*)&Alds[row*40+cg]   = *(const uint4*)src;
      *(uint4*)&Alds[row*40+cg+8] = *(const uint4*)(src+8);
    }
    { int kr = t>>3, ng = (t&7)*16;
      const u16* src = Tbf + (size_t)(kb+kr)*V + n0 + ng;
      uint4 x0 = *(const uint4*)src;
      uint4 x1 = *(const uint4*)(src + 8);
      const u16* px = (const u16*)&x0;
      const u16* py = (const u16*)&x1;
      #pragma unroll
      for (int jj=0; jj<8; ++jj) Blds[bswz(ng+jj, kr)] = px[jj];
      #pragma unroll
      for (int jj=0; jj<8; ++jj) Blds[bswz(ng+8+jj, kr)] = py[jj];
    }
    __syncthreads();
    bf16x8 av[4], bv[4];
    #pragma unroll
    for (int mf=0;mf<4;++mf) av[mf] = *(bf16x8*)&Alds[(wm*64+mf*16+l15)*40 + q*8];
    #pragma unroll
    for (int nf=0;nf<4;++nf){ int nn = wn*64+nf*16+l15; bv[nf] = *(bf16x8*)&Blds[bswz_rd(nn, q*8)]; }
    #pragma unroll
    for (int mf=0;mf<4;++mf)
      #pragma unroll
      for (int nf=0;nf<4;++nf)
        acc[mf][nf] = __builtin_amdgcn_mfma_f32_16x16x32_bf16(av[mf], bv[nf], acc[mf][nf], 0, 0, 0);
    __syncthreads();
  }
  float s2[4][4][4];
  #pragma unroll
  for (int mf=0;mf<4;++mf)
  #pragma unroll
  for (int nf=0;nf<4;++nf)
  #pragma unroll
  for (int reg=0;reg<4;++reg){ s2[mf][nf][reg] = acc[mf][nf][reg]; acc[mf][nf][reg] = 0.f; }
  // ---- phase 2: S1 = expCf @ expB (K=H) ----
  for (int it=0; it<64; ++it){
    int kb = it*32;
    { int row = t>>1, cg = (t&1)*16;
      const u16* src = expCf + (size_t)(m0+row)*H + kb + cg;
      *(uint4*)&Alds[row*40+cg]   = *(const uint4*)src;
      *(uint4*)&Alds[row*40+cg+8] = *(const uint4*)(src+8);
    }
    { int kr = t>>3, ng = (t&7)*16;
      const u16* src = expB + (size_t)(kb+kr)*V + n0 + ng;
      uint4 x0 = *(const uint4*)src;
      uint4 x1 = *(const uint4*)(src + 8);
      const u16* px = (const u16*)&x0;
      const u16* py = (const u16*)&x1;
      #pragma unroll
      for (int jj=0; jj<8; ++jj) Blds[bswz(ng+jj, kr)] = px[jj];
      #pragma unroll
      for (int jj=0; jj<8; ++jj) Blds[bswz(ng+8+jj, kr)] = py[jj];
    }
    __syncthreads();
    bf16x8 av[4], bv[4];
    #pragma unroll
    for (int mf=0;mf<4;++mf) av[mf] = *(bf16x8*)&Alds[(wm*64+mf*16+l15)*40 + q*8];
    #pragma unroll
    for (int nf=0;nf<4;++nf){ int nn = wn*64+nf*16+l15; bv[nf] = *(bf16x8*)&Blds[bswz_rd(nn, q*8)]; }
    #pragma unroll
    for (int mf=0;mf<4;++mf)
      #pragma unroll
      for (int nf=0;nf<4;++nf)
        acc[mf][nf] = __builtin_amdgcn_mfma_f32_16x16x32_bf16(av[mf], bv[nf], acc[mf][nf], 0, 0, 0);
    __syncthreads();
  }
  // ---- epilogue ----
  int b = mt*2 + wm;
  float mb = MB[b];
  #pragma unroll
  for (int nf=0; nf<4; ++nf){
    float v = 0.f;
    #pragma unroll
    for (int mf=0; mf<4; ++mf)
      #pragma unroll
      for (int reg=0; reg<4; ++reg)
        v += acc[mf][nf][reg] * s2[mf][nf][reg] * Wl[m0 + wm*64 + mf*16 + q*4 + reg];
    v += __shfl_xor(v, 16, 64);
    v += __shfl_xor(v, 32, 64);
    if (q == 0){
      int n = n0 + wn*64 + nf*16 + l15;
      out[(size_t)b*V + n] = v > 0.f ? (logf(v) + mb) : NEGV;
    }
  }
}

// ---------------- logits_ partial sums ----------------
__global__ __launch_bounds__(256) void k_lg2(const u16* __restrict__ expA, const u16* __restrict__ expB, float* __restrict__ S_){
  int bid = blockIdx.x; int kc = bid & 7, vt = bid >> 3; int t = threadIdx.x;  // grid 1000
  int v = vt*256 + t; int hh0 = kc*256;
  __shared__ float ea[BB][256];
  for (int i=0;i<8;++i){ int idx=i*256+t; int b=idx>>8, hl=idx&255; ea[b][hl]=bf2f(expA[b*H + hh0 + hl]); }
  __syncthreads();
  float acc[BB];
  #pragma unroll
  for(int b=0;b<BB;++b)acc[b]=0.f;
  for (int hl=0; hl<256; ++hl){
    float ex = bf2f(expB[(size_t)(hh0+hl)*V + v]);
    #pragma unroll
    for(int b=0;b<BB;++b) acc[b] += ea[b][hl]*ex;
  }
  #pragma unroll
  for(int b=0;b<BB;++b) atomicAdd(&S_[b*V + v], acc[b]);
}

__global__ __launch_bounds__(256) void k_lfin(const float* __restrict__ S_, const float* __restrict__ maxA, float* __restrict__ out){
  int idx = blockIdx.x*256 + threadIdx.x;  // 256000
  int b = idx / V;
  float sv = S_[idx];
  out[BB*V + idx] = sv > 0.f ? (logf(sv) + maxA[b]) : NEGV;
}

extern "C" void kernel_launch(void* const* d_in, const int* in_sizes, int n_in,
                              void* d_out, int out_size, void* d_ws, size_t ws_size,
                              hipStream_t stream){
  (void)in_sizes; (void)n_in; (void)out_size; (void)ws_size;
  const float* alpha_in  = (const float*)d_in[0];
  const float* beta_raw  = (const float*)d_in[1];
  const float* gamma_raw = (const float*)d_in[2];
  const float* T_mask    = (const float*)d_in[3];
  const float* VE_mask   = (const float*)d_in[4];
  const float* EV_mask   = (const float*)d_in[5];
  const float* accept    = (const float*)d_in[6];
  const float* rmask     = (const float*)d_in[7];
  const int* prefixes    = (const int*)d_in[8];
  const int* suffix      = (const int*)d_in[9];
  const int* states      = (const int*)d_in[10];
  float* out = (float*)d_out;

  char* base = (char*)d_ws;
  size_t off = 0;
  auto alloc = [&](size_t bytes)->char*{ char* r = base + off; off = (off + bytes + 255) & ~(size_t)255; return r; };
  // zero-initialized region (accumulators / encoded maxes / grid-barrier counters)
  float* PT    = (float*)alloc((size_t)TP1*H*SS*4);
  float* PA    = (float*)alloc((size_t)17*BB*H*4);
  u32*   MAXPA = (u32*)  alloc(17*BB*4);
  float* MUA   = (float*)alloc(17*BB*4);
  u32*   MU2   = (u32*)  alloc(TP1*SS*4);
  float* TwT   = (float*)alloc((size_t)H*EE*4);
  u32*   M1e   = (u32*)  alloc(BSZ*4);
  float* S_    = (float*)alloc((size_t)BB*V*4);
  u32*   BAR0  = (u32*)  alloc(256);   // ascan barrier counter (own cache line)
  u32*   BAR1  = (u32*)  alloc(256);   // suffix barrier counter
  u32*   BAR2  = (u32*)  alloc(256);   // scan barrier counter
  size_t zero_end = off;
  // write-before-read buffers
  float* alpha_f  = (float*)alloc((size_t)H*H*4);
  u16*   alpha_bf = (u16*)  alloc((size_t)H*H*2);
  float* rowlse   = (float*)alloc(H*4);
  float* G        = (float*)alloc(H*4);
  float* D        = (float*)alloc(PP*BB*4);
  float* YS       = (float*)alloc(2*H*4);
  u16*   EVbf     = (u16*)  alloc(EE*SS*2);
  u16*   VEbf     = (u16*)  alloc(SS*EE*2);
  float* Y2T      = (float*)alloc((size_t)H*SS*4);
  u16*   expB     = (u16*)  alloc((size_t)H*V*2);
  u16*   Tbf      = (u16*)  alloc((size_t)EE*V*2);
  float* Cfull    = (float*)alloc((size_t)BSZ*H*4);
  u16*   expCf    = (u16*)  alloc((size_t)BSZ*H*2);
  u16*   expA     = (u16*)  alloc(BB*H*2);
  float* maxA     = (float*)alloc(BB*4);
  u16*   A3       = (u16*)  alloc((size_t)BSZ*EE*2);
  float* W        = (float*)alloc(BSZ*4);
  float* MB       = (float*)alloc(BB*4);

  hipMemsetAsync(d_ws, 0, zero_end, stream);

  k_beta <<<H, 512, 0, stream>>>(beta_raw, rowlse, expB);
  k_alpha<<<H, 256, 0, stream>>>(alpha_in, alpha_f, alpha_bf);
  k_gamma<<<1, 256, 0, stream>>>(gamma_raw, G);
  k_prefd<<<PP*BB, 256, 0, stream>>>(beta_raw, rowlse, prefixes, D);
  k_mask <<<128, 256, 0, stream>>>(EV_mask, VE_mask, EVbf, VEbf);
  k_cvtT <<<EE*V/1024, 256, 0, stream>>>(T_mask, Tbf);
  k_a3   <<<1024, 256, 0, stream>>>(VE_mask, EV_mask, states, A3);

  // A-cache scan: all 16 steps in one kernel (software grid barrier)
  k_ascan_all<<<256, 256, 0, stream>>>(beta_raw, rowlse, alpha_f, G, D, prefixes, PA, MAXPA, MUA, BAR0);
  // suffix backward: all 7 steps in one kernel
  k_sufall<<<256, 256, 0, stream>>>(beta_raw, rowlse, alpha_f, suffix, YS, BAR1);

  // T_weights^T accumulate: [h][e] = sum_v expB[h,v]*Tbf[e,v]
  k_twgemm<<<640, 256, 0, stream>>>(expB, Tbf, TwT);
  k_twlog<<<H*EE/256, 256, 0, stream>>>(TwT);

  k_c0   <<<64, 256, 0, stream>>>(YS, accept, Y2T, MU2);
  // C-scan: pgemm(0) + 32x(cstep+pgemm) in one kernel (software grid barrier)
  k_scan <<<256, 256, 0, stream>>>(alpha_bf, PT, MU2, Y2T, TwT, EVbf, VEbf, BAR2);

  k_range<<<128, 256, 0, stream>>>(PT, MU2, rmask, PA, MUA, Cfull, M1e);
  k_mb   <<<1, 512, 0, stream>>>(M1e, W, MB);
  k_expcf<<<BSZ*H/256, 256, 0, stream>>>(Cfull, M1e, expCf);
  k_expa <<<BB, 256, 0, stream>>>(PA, MUA, expA, maxA);

  // fused: logits row 0
  k_flog<<<1000, 256, 0, stream>>>(expCf, expB, A3, Tbf, W, MB, out);

  // logits_ row 1
  k_lg2 <<<125*8, 256, 0, stream>>>(expA, expB, S_);
  k_lfin<<<BB*V/256, 256, 0, stream>>>(S_, maxA, out);
}

// Round 7
// 2059.767 us; speedup vs baseline: 1.9800x; 1.9800x over previous
//
#include <hip/hip_runtime.h>
#include <hip/hip_bf16.h>

#define H   2048
#define V   32000
#define SS  64
#define EE  512
#define BB  8
#define PP  16
#define LL  8
#define TT  32
#define TP1 33
#define BSZ 512   // B*S
#define NEGV -1e30f

typedef unsigned short u16;
typedef unsigned int   u32;
typedef short bf16x8 __attribute__((ext_vector_type(8)));
typedef float f32x4  __attribute__((ext_vector_type(4)));

__device__ __forceinline__ float bf2f(u16 x){ return __uint_as_float(((u32)x) << 16); }
__device__ __forceinline__ u16 f2bf(float f){
  u32 u = __float_as_uint(f);
  return (u16)((u + 0x7fffu + ((u >> 16) & 1u)) >> 16);
}
// monotonic float<->uint encoding for atomicMax on possibly-negative floats; init 0 is below enc(-inf)
__device__ __forceinline__ u32 encf(float f){ u32 u = __float_as_uint(f); return (u & 0x80000000u) ? ~u : (u | 0x80000000u); }
__device__ __forceinline__ float decf(u32 e){ u32 u = (e & 0x80000000u) ? (e & 0x7fffffffu) : ~e; return __uint_as_float(u); }

// XOR-swizzled index for transposed [n][k] LDS tiles with row stride 40 u16.
__device__ __forceinline__ int bswz(int n, int kr){
  return ((n*40 + (kr & ~7)) ^ ((n>>1) & 56)) + (kr & 7);
}
__device__ __forceinline__ int bswz_rd(int n, int k8){   // read base of 8 contiguous k at k8 (mult of 8)
  return (n*40 + k8) ^ ((n>>1) & 56);
}

// ---------------- beta: rowlse + expB (bf16), register-resident 3-pass ----------------
__global__ __launch_bounds__(512) void k_beta(const float* __restrict__ braw, float* __restrict__ rowlse, u16* __restrict__ expB){
  int h = blockIdx.x, t = threadIdx.x;
  __shared__ float red[8];
  __shared__ float red2[8];
  const float* row = braw + (size_t)h * V;
  uint2 stash[16];
  float m = -INFINITY;
  #pragma unroll
  for (int it = 0; it < 16; ++it){
    int idx = (it*512 + t)*4;
    if (idx < V){
      float4 x = *(const float4*)(row + idx);
      u16 b0=f2bf(x.x), b1=f2bf(x.y), b2=f2bf(x.z), b3=f2bf(x.w);
      stash[it] = make_uint2(((u32)b1<<16)|b0, ((u32)b3<<16)|b2);
      m = fmaxf(m, fmaxf(fmaxf(x.x,x.y),fmaxf(x.z,x.w)));
    }
  }
  for (int off=32; off; off>>=1) m = fmaxf(m, __shfl_xor(m, off, 64));
  if ((t&63)==0) red[t>>6] = m;
  __syncthreads();
  m = red[0];
  #pragma unroll
  for (int wv=1; wv<8; ++wv) m = fmaxf(m, red[wv]);
  float s0=0.f, s1=0.f;
  #pragma unroll
  for (int it = 0; it < 16; ++it){
    int idx = (it*512 + t)*4;
    if (idx < V){
      uint2 pk = stash[it];
      float e0 = expf(bf2f((u16)(pk.x      )) - m);
      float e1 = expf(bf2f((u16)(pk.x >> 16)) - m);
      float e2 = expf(bf2f((u16)(pk.y      )) - m);
      float e3 = expf(bf2f((u16)(pk.y >> 16)) - m);
      stash[it] = make_uint2(((u32)f2bf(e1)<<16)|f2bf(e0), ((u32)f2bf(e3)<<16)|f2bf(e2));
      s0 += e0 + e2; s1 += e1 + e3;
    }
  }
  float s = s0 + s1;
  for (int off=32; off; off>>=1) s += __shfl_xor(s, off, 64);
  if ((t&63)==0) red2[t>>6] = s;
  __syncthreads();
  s = (red2[0]+red2[1])+(red2[2]+red2[3])+(red2[4]+red2[5])+(red2[6]+red2[7]);
  if (t == 0) rowlse[h] = m + logf(s);
  float inv = 1.f / s;
  u16* orow = expB + (size_t)h*V;
  #pragma unroll
  for (int it = 0; it < 16; ++it){
    int idx = (it*512 + t)*4;
    if (idx < V){
      uint2 pk = stash[it];
      u16 a0 = f2bf(bf2f((u16)(pk.x      )) * inv);
      u16 a1 = f2bf(bf2f((u16)(pk.x >> 16)) * inv);
      u16 a2 = f2bf(bf2f((u16)(pk.y      )) * inv);
      u16 a3 = f2bf(bf2f((u16)(pk.y >> 16)) * inv);
      *(uint2*)(orow + idx) = make_uint2(((u32)a1<<16)|a0, ((u32)a3<<16)|a2);
    }
  }
}

// ---------------- alpha row softmax -> f32 + bf16 ----------------
__global__ __launch_bounds__(256) void k_alpha(const float* __restrict__ a, float* __restrict__ af, u16* __restrict__ abf){
  int r = blockIdx.x, t = threadIdx.x;
  __shared__ float ld[H];
  __shared__ float red[8];
  const float* row = a + (size_t)r * H;
  for (int i=0;i<8;++i){ int j=i*256+t; ld[j]=row[j]; }
  __syncthreads();
  float m=-INFINITY; for(int i=0;i<8;++i) m=fmaxf(m, ld[i*256+t]);
  for(int off=32;off;off>>=1) m=fmaxf(m,__shfl_xor(m,off,64));
  if((t&63)==0) red[t>>6]=m;
  __syncthreads();
  m=fmaxf(fmaxf(red[0],red[1]),fmaxf(red[2],red[3]));
  float s=0.f; for(int i=0;i<8;++i) s+=expf(ld[i*256+t]-m);
  for(int off=32;off;off>>=1) s+=__shfl_xor(s,off,64);
  if((t&63)==0) red[4+(t>>6)]=s;
  __syncthreads();
  s=red[4]+red[5]+red[6]+red[7];
  float inv=1.f/s;
  for(int i=0;i<8;++i){ int j=i*256+t; float e=expf(ld[j]-m)*inv; af[(size_t)r*H+j]=e; abf[(size_t)r*H+j]=f2bf(e); }
}

// ---------------- gamma log_softmax ----------------
__global__ __launch_bounds__(256) void k_gamma(const float* __restrict__ graw, float* __restrict__ G){
  int t = threadIdx.x;
  __shared__ float ld[H]; __shared__ float red[8];
  for (int i=0;i<8;++i){ int j=i*256+t; ld[j]=graw[j]; }
  __syncthreads();
  float m=-INFINITY; for(int i=0;i<8;++i) m=fmaxf(m, ld[i*256+t]);
  for(int off=32;off;off>>=1) m=fmaxf(m,__shfl_xor(m,off,64));
  if((t&63)==0) red[t>>6]=m;
  __syncthreads();
  m=fmaxf(fmaxf(red[0],red[1]),fmaxf(red[2],red[3]));
  float s=0.f; for(int i=0;i<8;++i) s+=expf(ld[i*256+t]-m);
  for(int off=32;off;off>>=1) s+=__shfl_xor(s,off,64);
  if((t&63)==0) red[4+(t>>6)]=s;
  __syncthreads();
  s=red[4]+red[5]+red[6]+red[7];
  float lse=m+logf(s);
  for(int i=0;i<8;++i){ int j=i*256+t; G[j]=ld[j]-lse; }
}

// ---------------- per (prefix step,b): max_h beta[h,tok] ----------------
__global__ __launch_bounds__(256) void k_prefd(const float* __restrict__ braw, const float* __restrict__ rowlse, const int* __restrict__ pref, float* __restrict__ D){
  int blk = blockIdx.x; int ts = blk >> 3, b = blk & 7; int t = threadIdx.x;
  int tok = pref[b*PP + ts];
  float m = -INFINITY;
  for (int i=0;i<8;++i){ int hh=i*256+t; m = fmaxf(m, braw[(size_t)hh*V + tok] - rowlse[hh]); }
  __shared__ float red[4];
  for(int off=32;off;off>>=1) m=fmaxf(m,__shfl_xor(m,off,64));
  if((t&63)==0) red[t>>6]=m;
  __syncthreads();
  if (t==0) D[ts*BB + b] = fmaxf(fmaxf(red[0],red[1]),fmaxf(red[2],red[3]));
}

// ---------------- masks -> bf16 ----------------
__global__ __launch_bounds__(256) void k_mask(const float* __restrict__ EV, const float* __restrict__ VE, u16* __restrict__ EVbf, u16* __restrict__ VEbf){
  int idx = blockIdx.x*256 + threadIdx.x;  // 32768
  EVbf[idx] = f2bf(EV[idx]);
  VEbf[idx] = f2bf(VE[idx]);
}

// ---------------- T_mask f32 -> bf16 (exact: 0/1) ----------------
__global__ __launch_bounds__(256) void k_cvtT(const float* __restrict__ T, u16* __restrict__ Tbf){
  int i = (blockIdx.x*256 + threadIdx.x)*4;   // grid 16000
  float4 x = *(const float4*)(T + i);
  *(uint2*)(Tbf + i) = make_uint2(((u32)f2bf(x.y)<<16)|f2bf(x.x), ((u32)f2bf(x.w)<<16)|f2bf(x.z));
}

// ---------------- A3[bs][e] = VE[states[b],e]*EV[e,s] ----------------
__global__ __launch_bounds__(256) void k_a3(const float* __restrict__ VE, const float* __restrict__ EV, const int* __restrict__ states, u16* __restrict__ A3){
  int idx = blockIdx.x*256 + threadIdx.x;  // 262144
  int bs = idx >> 9, e = idx & 511;
  int b = bs >> 6, s = bs & 63;
  A3[idx] = f2bf(VE[states[b]*EE + e] * EV[e*SS + s]);
}

// ---------------- A-cache scan step (exp-domain, rescaled); grid 256 ----------------
__global__ __launch_bounds__(256) void k_ascan(const float* __restrict__ braw, const float* __restrict__ rowlse,
    const float* __restrict__ alpha_f, const float* __restrict__ G, const float* __restrict__ D,
    const int* __restrict__ pref, float* __restrict__ PA, u32* __restrict__ MAXPA, float* __restrict__ MUA, int tstep){
  int bid = blockIdx.x; int kc = bid & 31, jt = bid >> 5; int t = threadIdx.x;   // grid 256
  __shared__ float ey[BB][64];
  __shared__ float wred[4][BB];
  const float* PAprev = PA + (size_t)(tstep-1)*BB*H;
  float* PAcur = PA + (size_t)tstep*BB*H;
  for (int i = 0; i < 2; ++i){
    int idx = i*256 + t; int b = idx >> 6, hl = idx & 63; int hh = kc*64 + hl;
    int tok = pref[b*PP + (tstep-1)];
    float bcol = braw[(size_t)hh*V + tok] - rowlse[hh];
    float Db = D[(tstep-1)*BB + b];
    float v;
    if (tstep == 1){
      v = expf(G[hh] + bcol - Db);
    } else {
      float p = PAprev[b*H + hh];
      float mp = fmaxf(__uint_as_float(MAXPA[(tstep-1)*BB + b]), 1e-30f);
      v = p > 0.f ? p * (1.f/mp) * expf(bcol - Db) : 0.f;
    }
    ey[b][hl] = v;
  }
  __syncthreads();
  int j = jt*256 + t;
  float acc[BB];
  #pragma unroll
  for (int b=0;b<BB;++b) acc[b]=0.f;
  for (int hl = 0; hl < 64; ++hl){
    float a = alpha_f[(size_t)(kc*64 + hl)*H + j];
    #pragma unroll
    for (int b=0;b<BB;++b) acc[b] += ey[b][hl] * a;
  }
  #pragma unroll
  for (int b=0;b<BB;++b){
    atomicAdd(&PAcur[b*H + j], acc[b]);
    float mv = acc[b];
    for (int off=32;off;off>>=1) mv = fmaxf(mv, __shfl_xor(mv, off, 64));
    if ((t&63)==0) wred[t>>6][b] = mv;
  }
  __syncthreads();
  if (t < BB){
    float mv = fmaxf(fmaxf(wred[0][t],wred[1][t]),fmaxf(wred[2][t],wred[3][t]));
    atomicMax(&MAXPA[tstep*BB + t], __float_as_uint(fmaxf(mv, 0.f)));
  }
  if (bid == 0 && t < BB){
    float mu = MUA[(tstep-1)*BB + t];
    if (tstep > 1) mu += logf(fmaxf(__uint_as_float(MAXPA[(tstep-1)*BB + t]), 1e-30f));
    MUA[tstep*BB + t] = mu + D[(tstep-1)*BB + t];
  }
}

// ---------------- suffix backward step ----------------
__global__ __launch_bounds__(256) void k_suffix(const float* __restrict__ braw, const float* __restrict__ rowlse,
    const float* __restrict__ alpha_f, const int* __restrict__ suffix, float* __restrict__ YS, int step){
  int t = threadIdx.x, blk = blockIdx.x;   // grid 512
  __shared__ float ye[H]; __shared__ float red[4];
  const float* src = YS + (step & 1)*H;
  float* dst = YS + (1 - (step & 1))*H;
  int tok_in = suffix[LL-1];
  for (int i=0;i<8;++i){
    int jj = i*256 + t;
    ye[jj] = (step == 0) ? (braw[(size_t)jj*V + tok_in] - rowlse[jj]) : src[jj];
  }
  __syncthreads();
  float m=-INFINITY;
  for(int i=0;i<8;++i) m=fmaxf(m, ye[i*256+t]);
  for(int off=32;off;off>>=1) m=fmaxf(m,__shfl_xor(m,off,64));
  if((t&63)==0) red[t>>6]=m;
  __syncthreads();
  m=fmaxf(fmaxf(red[0],red[1]),fmaxf(red[2],red[3]));
  for (int i=0;i<8;++i){ int jj=i*256+t; ye[jj] = expf(ye[jj]-m); }
  __syncthreads();
  int w = t >> 6, lane = t & 63;
  int r = blk*4 + w;
  float acc = 0.f;
  for (int k2=0;k2<32;++k2){ int jj=k2*64+lane; acc += alpha_f[(size_t)r*H + jj]*ye[jj]; }
  for(int off=32;off;off>>=1) acc += __shfl_xor(acc,off,64);
  if (lane==0){
    int tok = suffix[LL-2-step];
    dst[r] = logf(acc) + m + (braw[(size_t)r*V + tok] - rowlse[r]);
  }
}

// ---------------- C-scan t=0 prep: Y2T = accept-masked y_suf, MU2[0] ----------------
__global__ __launch_bounds__(256) void k_c0(const float* __restrict__ YS, const float* __restrict__ accept, float* __restrict__ Y2T, u32* __restrict__ MU2){
  int blk = blockIdx.x, t = threadIdx.x;   // grid 64
  const float* ysuf = YS + H;
  int h0 = blk*32;
  for (int i=0;i<8;++i){
    int idx = i*256 + t; int r = idx >> 6, s = idx & 63;
    Y2T[(size_t)(h0+r)*SS + s] = accept[s] > 0.f ? ysuf[h0 + r] : NEGV;
  }
  if (blk == 0){
    __shared__ float red[4];
    float m=-INFINITY;
    for(int i=0;i<8;++i) m = fmaxf(m, ysuf[i*256+t]);
    for(int off=32;off;off>>=1) m=fmaxf(m,__shfl_xor(m,off,64));
    if((t&63)==0) red[t>>6]=m;
    __syncthreads();
    if (t < SS){
      float mm = fmaxf(fmaxf(red[0],red[1]),fmaxf(red[2],red[3]));
      MU2[t] = encf(accept[t] > 0.f ? mm : NEGV);
    }
  }
}

// ---------------- PT[t][j][s] = sum_h exp(Y2T[h][s]-mu[s]) * alpha[j][h]  (MFMA, split-K 16, grid 256) ----------------
__global__ __launch_bounds__(256) void k_pgemm(const u16* __restrict__ abf, const float* __restrict__ Y2T, const u32* __restrict__ MU2t, float* __restrict__ PTt){
  int bid = blockIdx.x; int kc = bid & 15, mt = bid >> 4; int t = threadIdx.x;   // grid 256
  __shared__ u16 Alds[128*40];
  __shared__ u16 Blds[64*40];
  __shared__ float muld[SS];
  if (t < SS) muld[t] = decf(MU2t[t]);
  __syncthreads();
  int m0 = mt*128;
  int w = t >> 6, lane = t & 63, l15 = lane & 15, q = lane >> 4;
  f32x4 acc[2][4];
  for(int a=0;a<2;++a)for(int b=0;b<4;++b)for(int c=0;c<4;++c) acc[a][b][c]=0.f;
  for (int it=0; it<4; ++it){
    int kb = kc*128 + it*32;
    { int row = t >> 1, cg = (t & 1)*16;
      const u16* src = abf + (size_t)(m0+row)*H + kb + cg;
      *(uint4*)&Alds[row*40+cg]   = *(const uint4*)src;
      *(uint4*)&Alds[row*40+cg+8] = *(const uint4*)(src+8);
    }
    for (int i=0;i<8;++i){
      int idx = i*256 + t; int kr = idx >> 6, s = idx & 63;
      float y = Y2T[(size_t)(kb+kr)*SS + s];
      Blds[bswz(s, kr)] = f2bf(expf(y - muld[s]));
    }
    __syncthreads();
    bf16x8 bv[4];
    #pragma unroll
    for (int nf=0; nf<4; ++nf){ int nn = nf*16 + l15; bv[nf] = *(bf16x8*)&Blds[bswz_rd(nn, q*8)]; }
    #pragma unroll
    for (int mf=0; mf<2; ++mf){
      bf16x8 a = *(bf16x8*)&Alds[(w*32 + mf*16 + l15)*40 + q*8];
      #pragma unroll
      for (int nf=0; nf<4; ++nf)
        acc[mf][nf] = __builtin_amdgcn_mfma_f32_16x16x32_bf16(a, bv[nf], acc[mf][nf], 0, 0, 0);
    }
    __syncthreads();
  }
  #pragma unroll
  for (int mf=0;mf<2;++mf)
  #pragma unroll
  for (int nf=0;nf<4;++nf)
  #pragma unroll
  for (int reg=0;reg<4;++reg){
    int j = m0 + w*32 + mf*16 + q*4 + reg;
    int s = nf*16 + l15;
    atomicAdd(&PTt[(size_t)j*SS + s], acc[mf][nf][reg]);
  }
}

// ---------------- C-scan step: (transposed) EV-lse -> +Tw -> VE-lse, all MFMA ----------------
__global__ __launch_bounds__(256) void k_cstep(const float* __restrict__ PTprev, const u32* __restrict__ MU2prev,
    const float* __restrict__ TwT, const u16* __restrict__ EVbf, const u16* __restrict__ VEbf,
    float* __restrict__ Y2T, u32* __restrict__ MU2t){
  int blk = blockIdx.x, t = threadIdx.x;   // grid 128, 16 h-rows each
  int h0 = blk*16;
  __shared__ float ytile[16*64];
  __shared__ float muprev[SS];
  __shared__ float mx[16];
  __shared__ u32 mzenc[16];
  __shared__ float mzf[16];
  __shared__ u16 EYl[16*72];
  __shared__ u16 EZl[16*520];
  if (t < SS) muprev[t] = decf(MU2prev[t]);
  if (t >= 64 && t < 80) mzenc[t-64] = 0u;
  __syncthreads();
  for (int i=0;i<4;++i){
    int idx = i*256 + t; int r = idx >> 6, s = idx & 63;
    float p = PTprev[(size_t)(h0+r)*SS + s];
    ytile[r*64+s] = (p > 0.f) ? (logf(p) + muprev[s]) : NEGV;
  }
  __syncthreads();
  { int r = t >> 4, i4 = t & 15;
    float m = ytile[r*64 + i4*4];
    m = fmaxf(m, ytile[r*64 + i4*4 + 1]);
    m = fmaxf(m, ytile[r*64 + i4*4 + 2]);
    m = fmaxf(m, ytile[r*64 + i4*4 + 3]);
    for (int d=1; d<16; d<<=1) m = fmaxf(m, __shfl_xor(m, d, 64));
    if (i4 == 0) mx[r] = m;
  }
  __syncthreads();
  for (int i=0;i<4;++i){
    int idx = i*256 + t; int r = idx >> 6, s = idx & 63;
    EYl[r*72 + s] = f2bf(expf(ytile[r*64+s] - mx[r]));
  }
  __syncthreads();
  int w = t >> 6, lane = t & 63, l15 = lane & 15, q = lane >> 4;
  f32x4 acc1[8];
  for (int nf=0;nf<8;++nf) for(int c=0;c<4;++c) acc1[nf][c]=0.f;
  #pragma unroll
  for (int kf=0; kf<2; ++kf){
    bf16x8 a = *(bf16x8*)&EYl[l15*72 + kf*32 + q*8];
    #pragma unroll
    for (int nf=0; nf<8; ++nf){
      int e = w*128 + nf*16 + l15;
      bf16x8 b = *(const bf16x8*)&EVbf[(size_t)e*SS + kf*32 + q*8];
      acc1[nf] = __builtin_amdgcn_mfma_f32_16x16x32_bf16(a, b, acc1[nf], 0, 0, 0);
    }
  }
  #pragma unroll
  for (int nf=0; nf<8; ++nf){
    int e = w*128 + nf*16 + l15;
    #pragma unroll
    for (int reg=0; reg<4; ++reg){
      int r = q*4 + reg;
      float S1 = acc1[nf][reg];
      acc1[nf][reg] = (S1 > 0.f ? (logf(S1) + mx[r]) : NEGV) + TwT[(size_t)(h0+r)*EE + e];
    }
  }
  #pragma unroll
  for (int reg=0; reg<4; ++reg){
    float zm = acc1[0][reg];
    #pragma unroll
    for (int nf=1; nf<8; ++nf) zm = fmaxf(zm, acc1[nf][reg]);
    for (int d=1; d<16; d<<=1) zm = fmaxf(zm, __shfl_xor(zm, d, 64));
    if (l15 == 0) atomicMax(&mzenc[q*4 + reg], encf(zm));
  }
  __syncthreads();
  if (t < 16) mzf[t] = decf(mzenc[t]);
  __syncthreads();
  #pragma unroll
  for (int nf=0; nf<8; ++nf){
    int e = w*128 + nf*16 + l15;
    #pragma unroll
    for (int reg=0; reg<4; ++reg){
      int r = q*4 + reg;
      EZl[r*520 + e] = f2bf(expf(acc1[nf][reg] - mzf[r]));
    }
  }
  __syncthreads();
  f32x4 acc2;
  for(int c=0;c<4;++c) acc2[c]=0.f;
  #pragma unroll
  for (int kc2=0; kc2<16; ++kc2){
    bf16x8 a = *(bf16x8*)&EZl[l15*520 + kc2*32 + q*8];
    bf16x8 b = *(const bf16x8*)&VEbf[(size_t)(w*16 + l15)*EE + kc2*32 + q*8];
    acc2 = __builtin_amdgcn_mfma_f32_16x16x32_bf16(a, b, acc2, 0, 0, 0);
  }
  int s = w*16 + l15;
  float cm = -INFINITY;
  #pragma unroll
  for (int reg=0; reg<4; ++reg){
    int r = q*4 + reg;
    float S2 = acc2[reg];
    float y2 = S2 > 0.f ? (logf(S2) + mzf[r]) : NEGV;
    Y2T[(size_t)(h0+r)*SS + s] = y2;
    cm = fmaxf(cm, y2);
  }
  cm = fmaxf(cm, __shfl_xor(cm, 16, 64));
  cm = fmaxf(cm, __shfl_xor(cm, 32, 64));
  if (q == 0) atomicMax(&MU2t[s], encf(cm));
}

// ---------------- TwT GEMM: TwT[h][e] += sum_v expB[h,v]*Tbf[e,v]; both NT bf16 ----------------
__global__ __launch_bounds__(256) void k_twgemm(const u16* __restrict__ Abf, const u16* __restrict__ Bbf, float* __restrict__ Cacc){
  int bid = blockIdx.x; int t = threadIdx.x;   // grid 640 = 16 mt * 4 nt * 10 kc
  int kc = bid % 10; int rest = bid / 10;
  int nt = rest & 3; int mt = rest >> 2;
  int m0 = mt*128, n0 = nt*128;
  __shared__ u16 Alds[128*40];
  __shared__ u16 Blds[128*40];
  int w = t>>6, lane = t&63, l15 = lane&15, q = lane>>4;
  int wm = w >> 1, wn = w & 1;
  f32x4 acc[4][4];
  for(int a=0;a<4;++a)for(int b=0;b<4;++b)for(int c=0;c<4;++c)acc[a][b][c]=0.f;
  for (int it=0; it<100; ++it){
    int kb = (kc*100 + it)*32;
    { int row = t>>1, cg = (t&1)*16;
      const u16* srcA = Abf + (size_t)(m0+row)*V + kb + cg;
      *(uint4*)&Alds[row*40+cg]   = *(const uint4*)srcA;
      *(uint4*)&Alds[row*40+cg+8] = *(const uint4*)(srcA+8);
      const u16* srcB = Bbf + (size_t)(n0+row)*V + kb + cg;
      *(uint4*)&Blds[row*40+cg]   = *(const uint4*)srcB;
      *(uint4*)&Blds[row*40+cg+8] = *(const uint4*)(srcB+8);
    }
    __syncthreads();
    bf16x8 av[4], bv[4];
    #pragma unroll
    for (int mf=0;mf<4;++mf) av[mf] = *(bf16x8*)&Alds[(wm*64+mf*16+l15)*40 + q*8];
    #pragma unroll
    for (int nf=0;nf<4;++nf) bv[nf] = *(bf16x8*)&Blds[(wn*64+nf*16+l15)*40 + q*8];
    #pragma unroll
    for (int mf=0;mf<4;++mf)
      #pragma unroll
      for (int nf=0;nf<4;++nf)
        acc[mf][nf] = __builtin_amdgcn_mfma_f32_16x16x32_bf16(av[mf], bv[nf], acc[mf][nf], 0, 0, 0);
    __syncthreads();
  }
  #pragma unroll
  for (int mf=0;mf<4;++mf)
  #pragma unroll
  for (int nf=0;nf<4;++nf)
  #pragma unroll
  for (int reg=0;reg<4;++reg){
    int m = m0 + wm*64 + mf*16 + q*4 + reg;
    int n = n0 + wn*64 + nf*16 + l15;
    atomicAdd(&Cacc[(size_t)m*EE + n], acc[mf][nf][reg]);
  }
}

// ---------------- TwT = n2n(log(TwTacc)) in place ----------------
__global__ __launch_bounds__(256) void k_twlog(float* __restrict__ TwT){
  int idx = blockIdx.x*256 + threadIdx.x;
  float v = TwT[idx];
  TwT[idx] = v > 0.f ? logf(v) : NEGV;
}

// ---------------- range aggregation + A add -> Cfull, M1 ----------------
__global__ __launch_bounds__(256) void k_range(const float* __restrict__ PT, const u32* __restrict__ MU2,
    const float* __restrict__ rmask, const float* __restrict__ PA, const float* __restrict__ MUA,
    float* __restrict__ Cfull, u32* __restrict__ M1e){
  int blk = blockIdx.x, t = threadIdx.x; int h0 = blk*16;   // grid 128
  __shared__ float muf[TP1*SS];
  __shared__ float rm[BB*TP1];
  __shared__ float muA[BB];
  for (int i = t; i < TP1*SS; i += 256) muf[i] = decf(MU2[i]);
  for (int i = t; i < BB*TP1; i += 256) rm[i] = rmask[i];
  if (t < BB) muA[t] = MUA[16*BB + t];
  __syncthreads();
  const float* PA16 = PA + (size_t)16*BB*H;
  int s = t & 63; int hb = t >> 6;
  float tmax[BB];
  #pragma unroll
  for (int b=0;b<BB;++b) tmax[b] = -INFINITY;
  for (int i=0;i<4;++i){
    int h = h0 + hb*4 + i;
    float c[TP1];
    float M = -INFINITY;
    #pragma unroll
    for (int tt=0; tt<TP1; ++tt){
      float p = PT[(size_t)tt*(H*SS) + (size_t)h*SS + s];
      float cv = p > 0.f ? (logf(p) + muf[tt*SS + s]) : NEGV;
      c[tt] = cv; M = fmaxf(M, cv);
    }
    #pragma unroll
    for (int tt=0; tt<TP1; ++tt) c[tt] = expf(c[tt] - M);
    #pragma unroll
    for (int b=0;b<BB;++b){
      float a = 0.f;
      #pragma unroll
      for (int tt=0; tt<TP1; ++tt) a += rm[b*TP1 + tt]*c[tt];
      float cr = a > 0.f ? (logf(a) + M) : NEGV;
      float pa = PA16[b*H + h];
      float Ab = pa > 0.f ? (logf(pa) + muA[b]) : NEGV;
      float cf = Ab + cr;
      Cfull[((size_t)(b*SS + s))*H + h] = cf;
      tmax[b] = fmaxf(tmax[b], cf);
    }
  }
  #pragma unroll
  for (int b=0;b<BB;++b) atomicMax(&M1e[b*SS + s], encf(tmax[b]));
}

// ---------------- mb[b] = max_s M1[b,s]; W[b,s] = exp(M1-mb) ----------------
__global__ void k_mb(const u32* __restrict__ M1e, float* __restrict__ W, float* __restrict__ MB){
  int t = threadIdx.x;   // 512 threads; wave id == b
  float m1 = decf(M1e[t]);
  float m = m1;
  for (int off=32; off; off>>=1) m = fmaxf(m, __shfl_xor(m, off, 64));
  if ((t&63)==0) MB[t>>6] = m;
  W[t] = expf(m1 - m);
}

// ---------------- expCf bf16 ----------------
__global__ __launch_bounds__(256) void k_expcf(const float* __restrict__ Cfull, const u32* __restrict__ M1e, u16* __restrict__ expCf){
  int idx = blockIdx.x*256 + threadIdx.x;
  int bs = idx >> 11;
  expCf[idx] = f2bf(expf(Cfull[idx] - decf(M1e[bs])));
}

// ---------------- expA / maxA for logits_ ----------------
__global__ __launch_bounds__(256) void k_expa(const float* __restrict__ PA, const float* __restrict__ MUA, u16* __restrict__ expA, float* __restrict__ maxA){
  int b = blockIdx.x, t = threadIdx.x;
  const float* PA16 = PA + (size_t)16*BB*H + (size_t)b*H;
  __shared__ float al[H]; __shared__ float red[4];
  float mua = MUA[16*BB + b];
  for (int i=0;i<8;++i){ int h=i*256+t; float p=PA16[h]; al[h] = p>0.f ? (logf(p)+mua) : NEGV; }
  __syncthreads();
  float m=-INFINITY; for(int i=0;i<8;++i) m=fmaxf(m, al[i*256+t]);
  for(int off=32;off;off>>=1) m=fmaxf(m,__shfl_xor(m,off,64));
  if((t&63)==0) red[t>>6]=m;
  __syncthreads();
  m=fmaxf(fmaxf(red[0],red[1]),fmaxf(red[2],red[3]));
  if (t==0) maxA[b]=m;
  for (int i=0;i<8;++i){ int h=i*256+t; expA[b*H+h]=f2bf(expf(al[h]-m)); }
}

// ---------------- fused logits: S2 (K=512) stash, S1 (K=2048), combine + lse_s in-register ----------------
// logits[b,v] = log( sum_s S1[b,s,v]*S2[b,s,v]*exp(M1[b,s]-mb[b]) ) + mb[b]
// Block order: mt FASTEST (bid&3) so the 4 blocks sharing an expB/Tbf column slice are
// dispatch-adjacent and co-resident -> redundant reads hit L2/L3 instead of HBM.
__global__ __launch_bounds__(256) void k_flog(const u16* __restrict__ expCf, const u16* __restrict__ expB,
    const u16* __restrict__ A3, const u16* __restrict__ Tbf,
    const float* __restrict__ W, const float* __restrict__ MB, float* __restrict__ out){
  int bid = blockIdx.x; int t = threadIdx.x;   // grid 1000 = 250 nt * 4 mt (mt fastest)
  int mt = bid & 3, nt = bid >> 2;
  int m0 = mt*128, n0 = nt*128;
  __shared__ u16 Alds[128*40];
  __shared__ u16 Blds[128*40];
  __shared__ float Wl[BSZ];
  for (int i=t; i<BSZ; i+=256) Wl[i] = W[i];
  int w = t>>6, lane = t&63, l15 = lane&15, q = lane>>4;
  int wm = w >> 1, wn = w & 1;
  f32x4 acc[4][4];
  for(int a=0;a<4;++a)for(int b=0;b<4;++b)for(int c=0;c<4;++c)acc[a][b][c]=0.f;
  // ---- phase 1: S2 = A3 @ Tbf (K=EE) ----
  for (int it=0; it<16; ++it){
    int kb = it*32;
    { int row = t>>1, cg = (t&1)*16;
      const u16* src = A3 + (size_t)(m0+row)*EE + kb + cg;
      *(uint4*)&Alds[row*40+cg]   = *(const uint4*)src;
      *(uint4*)&Alds[row*40+cg+8] = *(const uint4*)(src+8);
    }
    { int kr = t>>3, ng = (t&7)*16;
      const u16* src = Tbf + (size_t)(kb+kr)*V + n0 + ng;
      uint4 x0 = *(const uint4*)src;
      uint4 x1 = *(const uint4*)(src + 8);
      const u16* px = (const u16*)&x0;
      const u16* py = (const u16*)&x1;
      #pragma unroll
      for (int jj=0; jj<8; ++jj) Blds[bswz(ng+jj, kr)] = px[jj];
      #pragma unroll
      for (int jj=0; jj<8; ++jj) Blds[bswz(ng+8+jj, kr)] = py[jj];
    }
    __syncthreads();
    bf16x8 av[4], bv[4];
    #pragma unroll
    for (int mf=0;mf<4;++mf) av[mf] = *(bf16x8*)&Alds[(wm*64+mf*16+l15)*40 + q*8];
    #pragma unroll
    for (int nf=0;nf<4;++nf){ int nn = wn*64+nf*16+l15; bv[nf] = *(bf16x8*)&Blds[bswz_rd(nn, q*8)]; }
    #pragma unroll
    for (int mf=0;mf<4;++mf)
      #pragma unroll
      for (int nf=0;nf<4;++nf)
        acc[mf][nf] = __builtin_amdgcn_mfma_f32_16x16x32_bf16(av[mf], bv[nf], acc[mf][nf], 0, 0, 0);
    __syncthreads();
  }
  float s2[4][4][4];
  #pragma unroll
  for (int mf=0;mf<4;++mf)
  #pragma unroll
  for (int nf=0;nf<4;++nf)
  #pragma unroll
  for (int reg=0;reg<4;++reg){ s2[mf][nf][reg] = acc[mf][nf][reg]; acc[mf][nf][reg] = 0.f; }
  // ---- phase 2: S1 = expCf @ expB (K=H) ----
  for (int it=0; it<64; ++it){
    int kb = it*32;
    { int row = t>>1, cg = (t&1)*16;
      const u16* src = expCf + (size_t)(m0+row)*H + kb + cg;
      *(uint4*)&Alds[row*40+cg]   = *(const uint4*)src;
      *(uint4*)&Alds[row*40+cg+8] = *(const uint4*)(src+8);
    }
    { int kr = t>>3, ng = (t&7)*16;
      const u16* src = expB + (size_t)(kb+kr)*V + n0 + ng;
      uint4 x0 = *(const uint4*)src;
      uint4 x1 = *(const uint4*)(src + 8);
      const u16* px = (const u16*)&x0;
      const u16* py = (const u16*)&x1;
      #pragma unroll
      for (int jj=0; jj<8; ++jj) Blds[bswz(ng+jj, kr)] = px[jj];
      #pragma unroll
      for (int jj=0; jj<8; ++jj) Blds[bswz(ng+8+jj, kr)] = py[jj];
    }
    __syncthreads();
    bf16x8 av[4], bv[4];
    #pragma unroll
    for (int mf=0;mf<4;++mf) av[mf] = *(bf16x8*)&Alds[(wm*64+mf*16+l15)*40 + q*8];
    #pragma unroll
    for (int nf=0;nf<4;++nf){ int nn = wn*64+nf*16+l15; bv[nf] = *(bf16x8*)&Blds[bswz_rd(nn, q*8)]; }
    #pragma unroll
    for (int mf=0;mf<4;++mf)
      #pragma unroll
      for (int nf=0;nf<4;++nf)
        acc[mf][nf] = __builtin_amdgcn_mfma_f32_16x16x32_bf16(av[mf], bv[nf], acc[mf][nf], 0, 0, 0);
    __syncthreads();
  }
  // ---- epilogue: each wave's 64 rows == one b; reduce over s in-register + 2 shuffles ----
  int b = mt*2 + wm;
  float mb = MB[b];
  #pragma unroll
  for (int nf=0; nf<4; ++nf){
    float v = 0.f;
    #pragma unroll
    for (int mf=0; mf<4; ++mf)
      #pragma unroll
      for (int reg=0; reg<4; ++reg)
        v += acc[mf][nf][reg] * s2[mf][nf][reg] * Wl[m0 + wm*64 + mf*16 + q*4 + reg];
    v += __shfl_xor(v, 16, 64);
    v += __shfl_xor(v, 32, 64);
    if (q == 0){
      int n = n0 + wn*64 + nf*16 + l15;
      out[(size_t)b*V + n] = v > 0.f ? (logf(v) + mb) : NEGV;
    }
  }
}

// ---------------- logits_ partial sums ----------------
__global__ __launch_bounds__(256) void k_lg2(const u16* __restrict__ expA, const u16* __restrict__ expB, float* __restrict__ S_){
  int bid = blockIdx.x; int kc = bid & 7, vt = bid >> 3; int t = threadIdx.x;  // grid 1000
  int v = vt*256 + t; int hh0 = kc*256;
  __shared__ float ea[BB][256];
  for (int i=0;i<8;++i){ int idx=i*256+t; int b=idx>>8, hl=idx&255; ea[b][hl]=bf2f(expA[b*H + hh0 + hl]); }
  __syncthreads();
  float acc[BB];
  #pragma unroll
  for(int b=0;b<BB;++b)acc[b]=0.f;
  for (int hl=0; hl<256; ++hl){
    float ex = bf2f(expB[(size_t)(hh0+hl)*V + v]);
    #pragma unroll
    for(int b=0;b<BB;++b) acc[b] += ea[b][hl]*ex;
  }
  #pragma unroll
  for(int b=0;b<BB;++b) atomicAdd(&S_[b*V + v], acc[b]);
}

__global__ __launch_bounds__(256) void k_lfin(const float* __restrict__ S_, const float* __restrict__ maxA, float* __restrict__ out){
  int idx = blockIdx.x*256 + threadIdx.x;  // 256000
  int b = idx / V;
  float sv = S_[idx];
  out[BB*V + idx] = sv > 0.f ? (logf(sv) + maxA[b]) : NEGV;
}

extern "C" void kernel_launch(void* const* d_in, const int* in_sizes, int n_in,
                              void* d_out, int out_size, void* d_ws, size_t ws_size,
                              hipStream_t stream){
  (void)in_sizes; (void)n_in; (void)out_size; (void)ws_size;
  const float* alpha_in  = (const float*)d_in[0];
  const float* beta_raw  = (const float*)d_in[1];
  const float* gamma_raw = (const float*)d_in[2];
  const float* T_mask    = (const float*)d_in[3];
  const float* VE_mask   = (const float*)d_in[4];
  const float* EV_mask   = (const float*)d_in[5];
  const float* accept    = (const float*)d_in[6];
  const float* rmask     = (const float*)d_in[7];
  const int* prefixes    = (const int*)d_in[8];
  const int* suffix      = (const int*)d_in[9];
  const int* states      = (const int*)d_in[10];
  float* out = (float*)d_out;

  char* base = (char*)d_ws;
  size_t off = 0;
  auto alloc = [&](size_t bytes)->char*{ char* r = base + off; off = (off + bytes + 255) & ~(size_t)255; return r; };
  // zero-initialized region (accumulators / encoded maxes)
  float* PT    = (float*)alloc((size_t)TP1*H*SS*4);
  float* PA    = (float*)alloc((size_t)17*BB*H*4);
  u32*   MAXPA = (u32*)  alloc(17*BB*4);
  float* MUA   = (float*)alloc(17*BB*4);
  u32*   MU2   = (u32*)  alloc(TP1*SS*4);
  float* TwT   = (float*)alloc((size_t)H*EE*4);
  u32*   M1e   = (u32*)  alloc(BSZ*4);
  float* S_    = (float*)alloc((size_t)BB*V*4);
  size_t zero_end = off;
  // write-before-read buffers
  float* alpha_f  = (float*)alloc((size_t)H*H*4);
  u16*   alpha_bf = (u16*)  alloc((size_t)H*H*2);
  float* rowlse   = (float*)alloc(H*4);
  float* G        = (float*)alloc(H*4);
  float* D        = (float*)alloc(PP*BB*4);
  float* YS       = (float*)alloc(2*H*4);
  u16*   EVbf     = (u16*)  alloc(EE*SS*2);
  u16*   VEbf     = (u16*)  alloc(SS*EE*2);
  float* Y2T      = (float*)alloc((size_t)H*SS*4);
  u16*   expB     = (u16*)  alloc((size_t)H*V*2);
  u16*   Tbf      = (u16*)  alloc((size_t)EE*V*2);
  float* Cfull    = (float*)alloc((size_t)BSZ*H*4);
  u16*   expCf    = (u16*)  alloc((size_t)BSZ*H*2);
  u16*   expA     = (u16*)  alloc(BB*H*2);
  float* maxA     = (float*)alloc(BB*4);
  u16*   A3       = (u16*)  alloc((size_t)BSZ*EE*2);
  float* W        = (float*)alloc(BSZ*4);
  float* MB       = (float*)alloc(BB*4);

  hipMemsetAsync(d_ws, 0, zero_end, stream);

  k_beta <<<H, 512, 0, stream>>>(beta_raw, rowlse, expB);
  k_alpha<<<H, 256, 0, stream>>>(alpha_in, alpha_f, alpha_bf);
  k_gamma<<<1, 256, 0, stream>>>(gamma_raw, G);
  k_prefd<<<PP*BB, 256, 0, stream>>>(beta_raw, rowlse, prefixes, D);
  k_mask <<<128, 256, 0, stream>>>(EV_mask, VE_mask, EVbf, VEbf);
  k_cvtT <<<EE*V/1024, 256, 0, stream>>>(T_mask, Tbf);
  k_a3   <<<1024, 256, 0, stream>>>(VE_mask, EV_mask, states, A3);

  for (int t = 1; t <= PP; ++t)
    k_ascan<<<256, 256, 0, stream>>>(beta_raw, rowlse, alpha_f, G, D, prefixes, PA, MAXPA, MUA, t);
  for (int i = 0; i < LL-1; ++i)
    k_suffix<<<512, 256, 0, stream>>>(beta_raw, rowlse, alpha_f, suffix, YS, i);

  // T_weights^T accumulate: [h][e] = sum_v expB[h,v]*Tbf[e,v]
  k_twgemm<<<640, 256, 0, stream>>>(expB, Tbf, TwT);
  k_twlog<<<H*EE/256, 256, 0, stream>>>(TwT);

  k_c0   <<<64, 256, 0, stream>>>(YS, accept, Y2T, MU2);
  k_pgemm<<<256, 256, 0, stream>>>(alpha_bf, Y2T, MU2, PT);
  for (int t = 1; t <= TT; ++t){
    k_cstep<<<128, 256, 0, stream>>>(PT + (size_t)(t-1)*H*SS, MU2 + (t-1)*SS, TwT, EVbf, VEbf, Y2T, MU2 + t*SS);
    k_pgemm<<<256, 256, 0, stream>>>(alpha_bf, Y2T, MU2 + t*SS, PT + (size_t)t*H*SS);
  }

  k_range<<<128, 256, 0, stream>>>(PT, MU2, rmask, PA, MUA, Cfull, M1e);
  k_mb   <<<1, 512, 0, stream>>>(M1e, W, MB);
  k_expcf<<<BSZ*H/256, 256, 0, stream>>>(Cfull, M1e, expCf);
  k_expa <<<BB, 256, 0, stream>>>(PA, MUA, expA, maxA);

  // fused: logits row 0
  k_flog<<<1000, 256, 0, stream>>>(expCf, expB, A3, Tbf, W, MB, out);

  // logits_ row 1
  k_lg2 <<<125*8, 256, 0, stream>>>(expA, expB, S_);
  k_lfin<<<BB*V/256, 256, 0, stream>>>(S_, maxA, out);
}